// Round 1
// baseline (363.634 us; speedup 1.0000x reference)
//
#include <hip/hip_runtime.h>

// ---------------------------------------------------------------------------
// Types / helpers
// ---------------------------------------------------------------------------
typedef __attribute__((ext_vector_type(8))) short bf16x8;   // 8 bf16 = 4 VGPR
typedef __attribute__((ext_vector_type(4))) short bf16x4;   // 8 bytes
typedef __attribute__((ext_vector_type(4))) float f32x4;    // MFMA acc

static __device__ __forceinline__ short f2bf(float f) {
    union { float f; unsigned u; } v; v.f = f;
    unsigned r = v.u + 0x7fffu + ((v.u >> 16) & 1u);   // RNE
    return (short)(r >> 16);
}

#define HEADS 16
#define DHEAD 64
#define NSEQ  2048
#define DIM   1024
#define BATCH 2
#define ROWS  (BATCH * NSEQ)          // 4096
#define NQKV  (3 * HEADS * DHEAD)     // 3072

// ---------------------------------------------------------------------------
// RMSNorm: xn = x / max(||x||,eps) * sqrt(dim) * gamma   (fp32 in, bf16 out)
// one block per row, 256 threads, float4 per thread
// ---------------------------------------------------------------------------
__global__ __launch_bounds__(256) void rmsnorm_kernel(const float* __restrict__ x,
                                                      const float* __restrict__ gamma,
                                                      short* __restrict__ xn) {
    const int row = blockIdx.x;
    const int t = threadIdx.x;
    const float4 v = ((const float4*)(x + (size_t)row * DIM))[t];
    float s = v.x * v.x + v.y * v.y + v.z * v.z + v.w * v.w;
#pragma unroll
    for (int off = 32; off > 0; off >>= 1) s += __shfl_down(s, off, 64);
    __shared__ float part[4];
    if ((t & 63) == 0) part[t >> 6] = s;
    __syncthreads();
    const float tot = part[0] + part[1] + part[2] + part[3];
    const float scale = 32.0f / fmaxf(sqrtf(tot), 1e-12f);   // sqrt(1024)=32
    const float4 g = ((const float4*)gamma)[t];
    bf16x4 o;
    o[0] = f2bf(v.x * scale * g.x);
    o[1] = f2bf(v.y * scale * g.y);
    o[2] = f2bf(v.z * scale * g.z);
    o[3] = f2bf(v.w * scale * g.w);
    *(bf16x4*)(xn + (size_t)row * DIM + t * 4) = o;
}

// ---------------------------------------------------------------------------
// Transpose + cast: in fp32 [R][C] -> out bf16 [C][R]  (32x32 LDS tiles)
// ---------------------------------------------------------------------------
__global__ __launch_bounds__(256) void transpose_cast(const float* __restrict__ in,
                                                      short* __restrict__ out,
                                                      int R, int C) {
    __shared__ float tile[32][33];
    const int tx = threadIdx.x & 31, ty = threadIdx.x >> 5;   // ty 0..7
    const int gx = blockIdx.x * 32, gy = blockIdx.y * 32;
#pragma unroll
    for (int i = 0; i < 4; ++i)
        tile[ty + i * 8][tx] = in[(size_t)(gy + ty + i * 8) * C + gx + tx];
    __syncthreads();
#pragma unroll
    for (int i = 0; i < 4; ++i)
        out[(size_t)(gx + ty + i * 8) * R + gy + tx] = f2bf(tile[tx][ty + i * 8]);
}

// ---------------------------------------------------------------------------
// GEMM: C[M x N] = A[M x K] * Bt[N x K]^T, bf16 in, fp32 acc.
// Block 256 thr = 4 waves; tile 128x128; wave tile 64x64 (4x4 MFMA frags).
// MODE 0: scatter to q/k/v [3][b*h][n][d] bf16, scale q by 1/8.
// MODE 1: fp32 row-major output.
// ---------------------------------------------------------------------------
template <int MODE>
__global__ __launch_bounds__(256) void gemm_bt(const short* __restrict__ A,
                                               const short* __restrict__ Bt,
                                               void* __restrict__ Cout,
                                               int K, int N) {
    __shared__ alignas(16) short lds_a[128 * 40];   // pad 32 -> 40 (2-way, free)
    __shared__ alignas(16) short lds_b[128 * 40];
    const int tid = threadIdx.x;
    const int lane = tid & 63, wid = tid >> 6;
    const int quad = lane >> 4, l16 = lane & 15;
    const int wm = wid >> 1, wn = wid & 1;
    const int mb = blockIdx.y * 128, nb = blockIdx.x * 128;

    f32x4 acc[4][4];
#pragma unroll
    for (int i = 0; i < 4; ++i)
#pragma unroll
        for (int j = 0; j < 4; ++j) acc[i][j] = (f32x4){0.f, 0.f, 0.f, 0.f};

    const int srow = tid >> 2;            // 0..63
    const int scol = (tid & 3) * 8;       // 0,8,16,24

    for (int kb = 0; kb < K; kb += 32) {
        const bf16x8 a0 = *(const bf16x8*)&A[(size_t)(mb + srow) * K + kb + scol];
        const bf16x8 a1 = *(const bf16x8*)&A[(size_t)(mb + 64 + srow) * K + kb + scol];
        const bf16x8 b0 = *(const bf16x8*)&Bt[(size_t)(nb + srow) * K + kb + scol];
        const bf16x8 b1 = *(const bf16x8*)&Bt[(size_t)(nb + 64 + srow) * K + kb + scol];
        __syncthreads();   // previous iter's frag reads done
        *(bf16x8*)&lds_a[srow * 40 + scol] = a0;
        *(bf16x8*)&lds_a[(64 + srow) * 40 + scol] = a1;
        *(bf16x8*)&lds_b[srow * 40 + scol] = b0;
        *(bf16x8*)&lds_b[(64 + srow) * 40 + scol] = b1;
        __syncthreads();
        bf16x8 af[4], bfr[4];
#pragma unroll
        for (int mt = 0; mt < 4; ++mt)
            af[mt] = *(const bf16x8*)&lds_a[(wm * 64 + mt * 16 + l16) * 40 + quad * 8];
#pragma unroll
        for (int nt = 0; nt < 4; ++nt)
            bfr[nt] = *(const bf16x8*)&lds_b[(wn * 64 + nt * 16 + l16) * 40 + quad * 8];
#pragma unroll
        for (int mt = 0; mt < 4; ++mt)
#pragma unroll
            for (int nt = 0; nt < 4; ++nt)
                acc[mt][nt] = __builtin_amdgcn_mfma_f32_16x16x32_bf16(af[mt], bfr[nt],
                                                                      acc[mt][nt], 0, 0, 0);
    }

#pragma unroll
    for (int mt = 0; mt < 4; ++mt) {
#pragma unroll
        for (int nt = 0; nt < 4; ++nt) {
#pragma unroll
            for (int r = 0; r < 4; ++r) {
                const int grow = mb + wm * 64 + mt * 16 + quad * 4 + r;   // C row
                const int gcol = nb + wn * 64 + nt * 16 + l16;            // C col
                const float val = acc[mt][nt][r];
                if (MODE == 0) {
                    // col -> (s, h, d); row -> (b, npos); dest [s][b*16+h][npos][d]
                    const int s3 = gcol >> 10, rem = gcol & 1023;
                    const int hh = rem >> 6, dd = rem & 63;
                    const int bb = grow >> 11, npos = grow & 2047;
                    const float vq = (s3 == 0) ? val * 0.125f : val;   // q * d^-0.5
                    ((short*)Cout)[(size_t)((s3 * 32 + bb * 16 + hh) * 2048 + npos) * 64 + dd] =
                        f2bf(vq);
                } else {
                    ((float*)Cout)[(size_t)grow * N + gcol] = val;
                }
            }
        }
    }
}

// ---------------------------------------------------------------------------
// Causal flash attention.
// q,k,v: [32][2048][64] bf16 (q pre-scaled). out: [4096][1024] bf16.
// Block: 4 waves = 64 queries; key tiles of 32 staged in LDS.
// ---------------------------------------------------------------------------
__global__ __launch_bounds__(256) void attn_kernel(const short* __restrict__ qg,
                                                   const short* __restrict__ kg,
                                                   const short* __restrict__ vg,
                                                   short* __restrict__ og) {
    const int bh = blockIdx.y;            // b*16 + h
    const int qt = blockIdx.x;            // 64-query tile
    const int q0 = qt * 64;
    const int tid = threadIdx.x;
    const int wid = tid >> 6, lane = tid & 63;
    const int quad = lane >> 4, l16 = lane & 15;
    const size_t base = (size_t)bh * NSEQ * DHEAD;

    // Q fragments (A-layout): m = l16, k = k0 + quad*8 + j
    const size_t qrow = base + (size_t)(q0 + wid * 16 + l16) * DHEAD;
    const bf16x8 qf0 = *(const bf16x8*)&qg[qrow + quad * 8];
    const bf16x8 qf1 = *(const bf16x8*)&qg[qrow + 32 + quad * 8];

    __shared__ alignas(16) short kbuf[32 * 72];       // K tile row-major, pad 64->72
    __shared__ alignas(16) short vtbuf[64 * 40];      // V tile transposed, pad 32->40
    __shared__ alignas(16) short pbuf[4][16 * 40];    // per-wave P transform

    float m_i[4], l_i[4];
    f32x4 accO[4];
#pragma unroll
    for (int r = 0; r < 4; ++r) { m_i[r] = -3.0e38f; l_i[r] = 0.f; }
#pragma unroll
    for (int nc = 0; nc < 4; ++nc) accO[nc] = (f32x4){0.f, 0.f, 0.f, 0.f};

    const int ntiles = qt * 2 + 2;         // keys 0 .. q0+63
    const int r_ = tid >> 3;               // 0..31 (staging row)
    const int c8 = (tid & 7) * 8;          // 0..56 (staging col)

    for (int t = 0; t < ntiles; ++t) {
        const int kb = t * 32;
        __syncthreads();   // protect vtbuf/kbuf from previous iteration's reads
        const bf16x8 kv = *(const bf16x8*)&kg[base + (size_t)(kb + r_) * DHEAD + c8];
        *(bf16x8*)&kbuf[r_ * 72 + c8] = kv;
        const bf16x8 vv = *(const bf16x8*)&vg[base + (size_t)(kb + r_) * DHEAD + c8];
#pragma unroll
        for (int jj = 0; jj < 8; ++jj) vtbuf[(c8 + jj) * 40 + r_] = vv[jj];
        __syncthreads();

        // S = Q K^T  (two 16-col blocks)
        f32x4 sf[2];
#pragma unroll
        for (int cb = 0; cb < 2; ++cb) {
            const bf16x8 kf0 = *(const bf16x8*)&kbuf[(cb * 16 + l16) * 72 + quad * 8];
            const bf16x8 kf1 = *(const bf16x8*)&kbuf[(cb * 16 + l16) * 72 + 32 + quad * 8];
            f32x4 z = (f32x4){0.f, 0.f, 0.f, 0.f};
            z = __builtin_amdgcn_mfma_f32_16x16x32_bf16(qf0, kf0, z, 0, 0, 0);
            sf[cb] = __builtin_amdgcn_mfma_f32_16x16x32_bf16(qf1, kf1, z, 0, 0, 0);
        }
        // causal mask: C-layout row = quad*4+r (query), col = l16 (key)
#pragma unroll
        for (int r = 0; r < 4; ++r) {
            const int myq = q0 + wid * 16 + quad * 4 + r;
#pragma unroll
            for (int cb = 0; cb < 2; ++cb) {
                const int key = kb + cb * 16 + l16;
                if (key > myq) sf[cb][r] = -3.0e38f;
            }
        }
        // online softmax
        float alpha[4];
#pragma unroll
        for (int r = 0; r < 4; ++r) {
            float rowm = fmaxf(sf[0][r], sf[1][r]);
#pragma unroll
            for (int off = 1; off < 16; off <<= 1)
                rowm = fmaxf(rowm, __shfl_xor(rowm, off, 16));
            const float nm = fmaxf(m_i[r], rowm);
            alpha[r] = __expf(m_i[r] - nm);
            m_i[r] = nm;
            const float p0 = __expf(sf[0][r] - nm);
            const float p1 = __expf(sf[1][r] - nm);
            sf[0][r] = p0; sf[1][r] = p1;
            float rs = p0 + p1;
#pragma unroll
            for (int off = 1; off < 16; off <<= 1) rs += __shfl_xor(rs, off, 16);
            l_i[r] = l_i[r] * alpha[r] + rs;
        }
#pragma unroll
        for (int nc = 0; nc < 4; ++nc)
#pragma unroll
            for (int r = 0; r < 4; ++r) accO[nc][r] *= alpha[r];
        // P: C-layout -> A-layout via LDS round trip
#pragma unroll
        for (int cb = 0; cb < 2; ++cb)
#pragma unroll
            for (int r = 0; r < 4; ++r)
                pbuf[wid][(quad * 4 + r) * 40 + cb * 16 + l16] = f2bf(sf[cb][r]);
        __syncthreads();   // drain own LDS writes (block-uniform)
        const bf16x8 pf = *(const bf16x8*)&pbuf[wid][l16 * 40 + quad * 8];
#pragma unroll
        for (int nc = 0; nc < 4; ++nc) {
            const bf16x8 vf = *(const bf16x8*)&vtbuf[(nc * 16 + l16) * 40 + quad * 8];
            accO[nc] = __builtin_amdgcn_mfma_f32_16x16x32_bf16(pf, vf, accO[nc], 0, 0, 0);
        }
    }

    // epilogue: out[b][npos][h*64 + d] bf16
    const int bb = bh >> 4, hh = bh & 15;
#pragma unroll
    for (int r = 0; r < 4; ++r) {
        const float inv = 1.0f / l_i[r];
        const int npos = q0 + wid * 16 + quad * 4 + r;
#pragma unroll
        for (int nc = 0; nc < 4; ++nc)
            og[(size_t)(bb * 2048 + npos) * 1024 + hh * 64 + nc * 16 + l16] =
                f2bf(accO[nc][r] * inv);
    }
}

// ---------------------------------------------------------------------------
// Launch
// ---------------------------------------------------------------------------
extern "C" void kernel_launch(void* const* d_in, const int* in_sizes, int n_in,
                              void* d_out, int out_size, void* d_ws, size_t ws_size,
                              hipStream_t stream) {
    const float* x     = (const float*)d_in[0];
    const float* gamma = (const float*)d_in[1];
    const float* w_qkv = (const float*)d_in[2];
    const float* w_out = (const float*)d_in[3];
    float* out = (float*)d_out;
    char* ws = (char*)d_ws;

    // workspace layout (bytes)
    short* xn     = (short*)(ws);                    //  8 MB: [4096][1024] bf16
    short* wqkvT  = (short*)(ws + 8388608);          //  6 MB: [3072][1024] bf16
    short* woutT  = (short*)(ws + 14680064);         //  2 MB: [1024][1024] bf16
    short* q      = (short*)(ws + 16777216);         // 24 MB: [3][32][2048][64] bf16
    short* k      = q + 32 * 2048 * 64;
    short* v      = k + 32 * 2048 * 64;
    short* attn   = (short*)(ws + 41943040);         //  8 MB: [4096][1024] bf16

    transpose_cast<<<dim3(NQKV / 32, DIM / 32), 256, 0, stream>>>(w_qkv, wqkvT, DIM, NQKV);
    transpose_cast<<<dim3(DIM / 32, DIM / 32), 256, 0, stream>>>(w_out, woutT, DIM, DIM);
    rmsnorm_kernel<<<ROWS, 256, 0, stream>>>(x, gamma, xn);
    gemm_bt<0><<<dim3(NQKV / 128, ROWS / 128), 256, 0, stream>>>(xn, wqkvT, q, DIM, NQKV);
    attn_kernel<<<dim3(NSEQ / 64, BATCH * HEADS), 256, 0, stream>>>(q, k, v, attn);
    gemm_bt<1><<<dim3(DIM / 128, ROWS / 128), 256, 0, stream>>>(attn, woutT, out, DIM, DIM);
}

// Round 2
// 320.357 us; speedup vs baseline: 1.1351x; 1.1351x over previous
//
#include <hip/hip_runtime.h>

// ---------------------------------------------------------------------------
// Types / helpers
// ---------------------------------------------------------------------------
typedef __attribute__((ext_vector_type(8))) short bf16x8;   // 8 bf16 = 4 VGPR
typedef __attribute__((ext_vector_type(4))) short bf16x4;   // 8 bytes
typedef __attribute__((ext_vector_type(4))) float f32x4;    // MFMA acc

static __device__ __forceinline__ short f2bf(float f) {
    union { float f; unsigned u; } v; v.f = f;
    unsigned r = v.u + 0x7fffu + ((v.u >> 16) & 1u);   // RNE
    return (short)(r >> 16);
}

#define HEADS 16
#define DHEAD 64
#define NSEQ  2048
#define DIM   1024
#define BATCH 2
#define ROWS  (BATCH * NSEQ)          // 4096
#define NQKV  (3 * HEADS * DHEAD)     // 3072

// ---------------------------------------------------------------------------
// RMSNorm: xn = x / max(||x||,eps) * sqrt(dim) * gamma   (fp32 in, bf16 out)
// ---------------------------------------------------------------------------
__global__ __launch_bounds__(256) void rmsnorm_kernel(const float* __restrict__ x,
                                                      const float* __restrict__ gamma,
                                                      short* __restrict__ xn) {
    const int row = blockIdx.x;
    const int t = threadIdx.x;
    const float4 v = ((const float4*)(x + (size_t)row * DIM))[t];
    float s = v.x * v.x + v.y * v.y + v.z * v.z + v.w * v.w;
#pragma unroll
    for (int off = 32; off > 0; off >>= 1) s += __shfl_down(s, off, 64);
    __shared__ float part[4];
    if ((t & 63) == 0) part[t >> 6] = s;
    __syncthreads();
    const float tot = part[0] + part[1] + part[2] + part[3];
    const float scale = 32.0f / fmaxf(sqrtf(tot), 1e-12f);   // sqrt(1024)=32
    const float4 g = ((const float4*)gamma)[t];
    bf16x4 o;
    o[0] = f2bf(v.x * scale * g.x);
    o[1] = f2bf(v.y * scale * g.y);
    o[2] = f2bf(v.z * scale * g.z);
    o[3] = f2bf(v.w * scale * g.w);
    *(bf16x4*)(xn + (size_t)row * DIM + t * 4) = o;
}

// ---------------------------------------------------------------------------
// Transpose + cast: in fp32 [R][C] -> out bf16 [C][R]  (32x32 LDS tiles)
// ---------------------------------------------------------------------------
__global__ __launch_bounds__(256) void transpose_cast(const float* __restrict__ in,
                                                      short* __restrict__ out,
                                                      int R, int C) {
    __shared__ float tile[32][33];
    const int tx = threadIdx.x & 31, ty = threadIdx.x >> 5;   // ty 0..7
    const int gx = blockIdx.x * 32, gy = blockIdx.y * 32;
#pragma unroll
    for (int i = 0; i < 4; ++i)
        tile[ty + i * 8][tx] = in[(size_t)(gy + ty + i * 8) * C + gx + tx];
    __syncthreads();
#pragma unroll
    for (int i = 0; i < 4; ++i)
        out[(size_t)(gx + ty + i * 8) * R + gy + tx] = f2bf(tile[tx][ty + i * 8]);
}

// ---------------------------------------------------------------------------
// Transpose V: v [32][2048][64] bf16 -> vt [32][64][2048] bf16
// ---------------------------------------------------------------------------
__global__ __launch_bounds__(256) void transpose_v(const short* __restrict__ v,
                                                   short* __restrict__ vt) {
    const int bh = blockIdx.y;
    const int n0 = blockIdx.x * 64;
    __shared__ short tile[64 * 72];
    const int r = threadIdx.x >> 3;          // 0..31
    const int c8 = (threadIdx.x & 7) * 8;    // 0..56
#pragma unroll
    for (int p = 0; p < 2; ++p)
        *(bf16x8*)&tile[(p * 32 + r) * 72 + c8] =
            *(const bf16x8*)&v[((size_t)bh * NSEQ + n0 + p * 32 + r) * DHEAD + c8];
    __syncthreads();
#pragma unroll
    for (int p = 0; p < 2; ++p) {
        const int d = p * 32 + r;
        bf16x8 o;
#pragma unroll
        for (int j = 0; j < 8; ++j) o[j] = tile[(c8 + j) * 72 + d];
        *(bf16x8*)&vt[((size_t)bh * DHEAD + d) * NSEQ + n0 + c8] = o;
    }
}

// ---------------------------------------------------------------------------
// GEMM: C[M x N] = A[M x K] * Bt[N x K]^T, bf16 in, fp32 acc.
// MODE 0: scatter to q/k/v [3][b*h][n][d] bf16, scale q by d^-0.5.
// MODE 1: fp32 row-major output.
// ---------------------------------------------------------------------------
template <int MODE>
__global__ __launch_bounds__(256) void gemm_bt(const short* __restrict__ A,
                                               const short* __restrict__ Bt,
                                               void* __restrict__ Cout,
                                               int K, int N) {
    __shared__ alignas(16) short lds_a[128 * 40];
    __shared__ alignas(16) short lds_b[128 * 40];
    const int tid = threadIdx.x;
    const int lane = tid & 63, wid = tid >> 6;
    const int quad = lane >> 4, l16 = lane & 15;
    const int wm = wid >> 1, wn = wid & 1;
    const int mb = blockIdx.y * 128, nb = blockIdx.x * 128;

    f32x4 acc[4][4];
#pragma unroll
    for (int i = 0; i < 4; ++i)
#pragma unroll
        for (int j = 0; j < 4; ++j) acc[i][j] = (f32x4){0.f, 0.f, 0.f, 0.f};

    const int srow = tid >> 2;
    const int scol = (tid & 3) * 8;

    for (int kb = 0; kb < K; kb += 32) {
        const bf16x8 a0 = *(const bf16x8*)&A[(size_t)(mb + srow) * K + kb + scol];
        const bf16x8 a1 = *(const bf16x8*)&A[(size_t)(mb + 64 + srow) * K + kb + scol];
        const bf16x8 b0 = *(const bf16x8*)&Bt[(size_t)(nb + srow) * K + kb + scol];
        const bf16x8 b1 = *(const bf16x8*)&Bt[(size_t)(nb + 64 + srow) * K + kb + scol];
        __syncthreads();
        *(bf16x8*)&lds_a[srow * 40 + scol] = a0;
        *(bf16x8*)&lds_a[(64 + srow) * 40 + scol] = a1;
        *(bf16x8*)&lds_b[srow * 40 + scol] = b0;
        *(bf16x8*)&lds_b[(64 + srow) * 40 + scol] = b1;
        __syncthreads();
        bf16x8 af[4], bfr[4];
#pragma unroll
        for (int mt = 0; mt < 4; ++mt)
            af[mt] = *(const bf16x8*)&lds_a[(wm * 64 + mt * 16 + l16) * 40 + quad * 8];
#pragma unroll
        for (int nt = 0; nt < 4; ++nt)
            bfr[nt] = *(const bf16x8*)&lds_b[(wn * 64 + nt * 16 + l16) * 40 + quad * 8];
#pragma unroll
        for (int mt = 0; mt < 4; ++mt)
#pragma unroll
            for (int nt = 0; nt < 4; ++nt)
                acc[mt][nt] = __builtin_amdgcn_mfma_f32_16x16x32_bf16(af[mt], bfr[nt],
                                                                      acc[mt][nt], 0, 0, 0);
    }

#pragma unroll
    for (int mt = 0; mt < 4; ++mt) {
#pragma unroll
        for (int nt = 0; nt < 4; ++nt) {
#pragma unroll
            for (int r = 0; r < 4; ++r) {
                const int grow = mb + wm * 64 + mt * 16 + quad * 4 + r;
                const int gcol = nb + wn * 64 + nt * 16 + l16;
                const float val = acc[mt][nt][r];
                if (MODE == 0) {
                    const int s3 = gcol >> 10, rem = gcol & 1023;
                    const int hh = rem >> 6, dd = rem & 63;
                    const int bb = grow >> 11, npos = grow & 2047;
                    const float vq = (s3 == 0) ? val * 0.125f : val;   // q * d^-0.5
                    ((short*)Cout)[(size_t)((s3 * 32 + bb * 16 + hh) * 2048 + npos) * 64 + dd] =
                        f2bf(vq);
                } else {
                    ((float*)Cout)[(size_t)grow * N + gcol] = val;
                }
            }
        }
    }
}

// ---------------------------------------------------------------------------
// Causal flash attention — ZERO block barriers.
// q,k: [32][2048][64] bf16 (q pre-scaled). vt: [32][64][2048] bf16.
// out: [4096][1024] bf16.
// Block = 4 waves; each wave owns 32 queries and runs independently
// (K/V MFMA fragments loaded directly from global, L2-resident).
// Only LDS use is the wave-private P layout transform (C-layout -> A-layout).
// ---------------------------------------------------------------------------
__global__ __launch_bounds__(256) void attn_kernel(const short* __restrict__ qg,
                                                   const short* __restrict__ kg,
                                                   const short* __restrict__ vtg,
                                                   short* __restrict__ og) {
    const int bh = blockIdx.x;            // b*16 + h  (x fast => resident blocks mix qt)
    const int qt = blockIdx.y;            // 128-query tile
    const int tid = threadIdx.x;
    const int wid = tid >> 6, lane = tid & 63;
    const int quad = lane >> 4, l16 = lane & 15;
    const size_t base = (size_t)bh * (NSEQ * DHEAD);
    const int qbase = qt * 128 + wid * 32;     // this wave's first query

    __shared__ alignas(16) short pbuf[4][32 * 72];   // wave-private P (stride 72: b128-aligned, 4-way write worst)
    short* const pb = pbuf[wid];

    // Q fragments (A-layout): m = l16, k = kh*32 + quad*8 + j
    bf16x8 qf[2][2];
#pragma unroll
    for (int mt = 0; mt < 2; ++mt)
#pragma unroll
        for (int kh = 0; kh < 2; ++kh)
            qf[mt][kh] = *(const bf16x8*)&qg[base + (size_t)(qbase + mt * 16 + l16) * DHEAD +
                                            kh * 32 + quad * 8];

    float mi[2][4], li[2][4];
    f32x4 accO[2][4];
#pragma unroll
    for (int mt = 0; mt < 2; ++mt)
#pragma unroll
        for (int r = 0; r < 4; ++r) { mi[mt][r] = -3.0e38f; li[mt][r] = 0.f; }
#pragma unroll
    for (int mt = 0; mt < 2; ++mt)
#pragma unroll
        for (int nc = 0; nc < 4; ++nc) accO[mt][nc] = (f32x4){0.f, 0.f, 0.f, 0.f};

    const int ntiles = qbase / 64 + 1;         // per-wave causal bound (waves diverge freely)

    for (int t = 0; t < ntiles; ++t) {
        const int kb = t * 64;

        // ---- S = Q K^T over a 32q x 64k tile ----
        f32x4 sf[2][4];
#pragma unroll
        for (int cb = 0; cb < 4; ++cb) {
            const short* kr = &kg[base + (size_t)(kb + cb * 16 + l16) * DHEAD];
            const bf16x8 kf0 = *(const bf16x8*)&kr[quad * 8];
            const bf16x8 kf1 = *(const bf16x8*)&kr[32 + quad * 8];
#pragma unroll
            for (int mt = 0; mt < 2; ++mt) {
                f32x4 z = (f32x4){0.f, 0.f, 0.f, 0.f};
                z = __builtin_amdgcn_mfma_f32_16x16x32_bf16(qf[mt][0], kf0, z, 0, 0, 0);
                sf[mt][cb] = __builtin_amdgcn_mfma_f32_16x16x32_bf16(qf[mt][1], kf1, z, 0, 0, 0);
            }
        }

        // ---- causal mask (only the diagonal tile(s); wave-uniform branch) ----
        if (kb + 64 > qbase) {
#pragma unroll
            for (int mt = 0; mt < 2; ++mt)
#pragma unroll
                for (int r = 0; r < 4; ++r) {
                    const int myq = qbase + mt * 16 + quad * 4 + r;
#pragma unroll
                    for (int cb = 0; cb < 4; ++cb) {
                        const int key = kb + cb * 16 + l16;
                        if (key > myq) sf[mt][cb][r] = -3.0e38f;
                    }
                }
        }

        // ---- online softmax (row = quad*4+r within 16-lane groups) ----
#pragma unroll
        for (int mt = 0; mt < 2; ++mt) {
#pragma unroll
            for (int r = 0; r < 4; ++r) {
                float rowm = fmaxf(fmaxf(sf[mt][0][r], sf[mt][1][r]),
                                   fmaxf(sf[mt][2][r], sf[mt][3][r]));
#pragma unroll
                for (int off = 1; off < 16; off <<= 1)
                    rowm = fmaxf(rowm, __shfl_xor(rowm, off, 16));
                const float nm = fmaxf(mi[mt][r], rowm);
                const float al = __expf(mi[mt][r] - nm);
                mi[mt][r] = nm;
                float rs = 0.f;
#pragma unroll
                for (int cb = 0; cb < 4; ++cb) {
                    const float p = __expf(sf[mt][cb][r] - nm);
                    sf[mt][cb][r] = p;
                    rs += p;
                }
#pragma unroll
                for (int off = 1; off < 16; off <<= 1) rs += __shfl_xor(rs, off, 16);
                li[mt][r] = li[mt][r] * al + rs;
#pragma unroll
                for (int nc = 0; nc < 4; ++nc) accO[mt][nc][r] *= al;
            }
        }

        // ---- P: C-layout -> A-layout via wave-private LDS (no block barrier:
        //      same-wave LDS RAW is ordered by the in-order LDS pipe + lgkmcnt) ----
#pragma unroll
        for (int mt = 0; mt < 2; ++mt)
#pragma unroll
            for (int cb = 0; cb < 4; ++cb)
#pragma unroll
                for (int r = 0; r < 4; ++r)
                    pb[(mt * 16 + quad * 4 + r) * 72 + cb * 16 + l16] = f2bf(sf[mt][cb][r]);
        bf16x8 pf[2][2];
#pragma unroll
        for (int mt = 0; mt < 2; ++mt)
#pragma unroll
            for (int kh = 0; kh < 2; ++kh)
                pf[mt][kh] = *(const bf16x8*)&pb[(mt * 16 + l16) * 72 + kh * 32 + quad * 8];

        // ---- O += P V  (V^T fragments direct from global) ----
#pragma unroll
        for (int nc = 0; nc < 4; ++nc) {
            const short* vr = &vtg[base + (size_t)(nc * 16 + l16) * NSEQ + kb];
            const bf16x8 vf0 = *(const bf16x8*)&vr[quad * 8];
            const bf16x8 vf1 = *(const bf16x8*)&vr[32 + quad * 8];
#pragma unroll
            for (int mt = 0; mt < 2; ++mt) {
                accO[mt][nc] = __builtin_amdgcn_mfma_f32_16x16x32_bf16(pf[mt][0], vf0,
                                                                      accO[mt][nc], 0, 0, 0);
                accO[mt][nc] = __builtin_amdgcn_mfma_f32_16x16x32_bf16(pf[mt][1], vf1,
                                                                      accO[mt][nc], 0, 0, 0);
            }
        }
    }

    // ---- epilogue: out[b][npos][h*64 + d] bf16 ----
    const int bb = bh >> 4, hh = bh & 15;
#pragma unroll
    for (int mt = 0; mt < 2; ++mt)
#pragma unroll
        for (int r = 0; r < 4; ++r) {
            const float inv = 1.0f / li[mt][r];
            const int npos = qbase + mt * 16 + quad * 4 + r;
#pragma unroll
            for (int nc = 0; nc < 4; ++nc)
                og[(size_t)(bb * 2048 + npos) * 1024 + hh * 64 + nc * 16 + l16] =
                    f2bf(accO[mt][nc][r] * inv);
        }
}

// ---------------------------------------------------------------------------
// Launch
// ---------------------------------------------------------------------------
extern "C" void kernel_launch(void* const* d_in, const int* in_sizes, int n_in,
                              void* d_out, int out_size, void* d_ws, size_t ws_size,
                              hipStream_t stream) {
    const float* x     = (const float*)d_in[0];
    const float* gamma = (const float*)d_in[1];
    const float* w_qkv = (const float*)d_in[2];
    const float* w_out = (const float*)d_in[3];
    float* out = (float*)d_out;
    char* ws = (char*)d_ws;

    // workspace layout (bytes) — 50 MB total, same footprint as round 1
    short* xn     = (short*)(ws);                    //  8 MB: [4096][1024] bf16 (dead after gemm<0>)
    short* vt     = (short*)(ws);                    //  8 MB: [32][64][2048] bf16 (reuses xn)
    short* wqkvT  = (short*)(ws + 8388608);          //  6 MB: [3072][1024] bf16
    short* woutT  = (short*)(ws + 14680064);         //  2 MB: [1024][1024] bf16
    short* q      = (short*)(ws + 16777216);         // 24 MB: [3][32][2048][64] bf16
    short* k      = q + 32 * 2048 * 64;
    short* v      = k + 32 * 2048 * 64;
    short* attn   = (short*)(ws + 41943040);         //  8 MB: [4096][1024] bf16

    transpose_cast<<<dim3(NQKV / 32, DIM / 32), 256, 0, stream>>>(w_qkv, wqkvT, DIM, NQKV);
    transpose_cast<<<dim3(DIM / 32, DIM / 32), 256, 0, stream>>>(w_out, woutT, DIM, DIM);
    rmsnorm_kernel<<<ROWS, 256, 0, stream>>>(x, gamma, xn);
    gemm_bt<0><<<dim3(NQKV / 128, ROWS / 128), 256, 0, stream>>>(xn, wqkvT, q, DIM, NQKV);
    transpose_v<<<dim3(NSEQ / 64, 32), 256, 0, stream>>>(v, vt);   // xn dead -> vt
    attn_kernel<<<dim3(32, NSEQ / 128), 256, 0, stream>>>(q, k, vt, attn);
    gemm_bt<1><<<dim3(DIM / 128, ROWS / 128), 256, 0, stream>>>(attn, woutT, out, DIM, DIM);
}

// Round 3
// 220.474 us; speedup vs baseline: 1.6493x; 1.4530x over previous
//
#include <hip/hip_runtime.h>

// ---------------------------------------------------------------------------
// Types / helpers
// ---------------------------------------------------------------------------
typedef __attribute__((ext_vector_type(8))) short bf16x8;   // 8 bf16 = 4 VGPR
typedef __attribute__((ext_vector_type(4))) short bf16x4;   // 8 bytes
typedef __attribute__((ext_vector_type(4))) float f32x4;    // MFMA acc

static __device__ __forceinline__ short f2bf(float f) {
    union { float f; unsigned u; } v; v.f = f;
    unsigned r = v.u + 0x7fffu + ((v.u >> 16) & 1u);   // RNE
    return (short)(r >> 16);
}

// async global->LDS, 16B per lane; lds dest MUST be base + lane*16 (m97/m104)
static __device__ __forceinline__ void async_copy16(const short* g, short* l) {
    __builtin_amdgcn_global_load_lds((const __attribute__((address_space(1))) void*)g,
                                     (__attribute__((address_space(3))) void*)l,
                                     16, 0, 0);
}

#define HEADS 16
#define DHEAD 64
#define NSEQ  2048
#define DIM   1024
#define BATCH 2
#define ROWS  (BATCH * NSEQ)          // 4096
#define NQKV  (3 * HEADS * DHEAD)     // 3072

// ---------------------------------------------------------------------------
// RMSNorm: xn = x / max(||x||,eps) * sqrt(dim) * gamma   (fp32 in, bf16 out)
// ---------------------------------------------------------------------------
__global__ __launch_bounds__(256) void rmsnorm_kernel(const float* __restrict__ x,
                                                      const float* __restrict__ gamma,
                                                      short* __restrict__ xn) {
    const int row = blockIdx.x;
    const int t = threadIdx.x;
    const float4 v = ((const float4*)(x + (size_t)row * DIM))[t];
    float s = v.x * v.x + v.y * v.y + v.z * v.z + v.w * v.w;
#pragma unroll
    for (int off = 32; off > 0; off >>= 1) s += __shfl_down(s, off, 64);
    __shared__ float part[4];
    if ((t & 63) == 0) part[t >> 6] = s;
    __syncthreads();
    const float tot = part[0] + part[1] + part[2] + part[3];
    const float scale = 32.0f / fmaxf(sqrtf(tot), 1e-12f);   // sqrt(1024)=32
    const float4 g = ((const float4*)gamma)[t];
    bf16x4 o;
    o[0] = f2bf(v.x * scale * g.x);
    o[1] = f2bf(v.y * scale * g.y);
    o[2] = f2bf(v.z * scale * g.z);
    o[3] = f2bf(v.w * scale * g.w);
    *(bf16x4*)(xn + (size_t)row * DIM + t * 4) = o;
}

// ---------------------------------------------------------------------------
// Transpose + cast: in fp32 [R][C] -> out bf16 [C][R]  (32x32 LDS tiles)
// ---------------------------------------------------------------------------
__global__ __launch_bounds__(256) void transpose_cast(const float* __restrict__ in,
                                                      short* __restrict__ out,
                                                      int R, int C) {
    __shared__ float tile[32][33];
    const int tx = threadIdx.x & 31, ty = threadIdx.x >> 5;   // ty 0..7
    const int gx = blockIdx.x * 32, gy = blockIdx.y * 32;
#pragma unroll
    for (int i = 0; i < 4; ++i)
        tile[ty + i * 8][tx] = in[(size_t)(gy + ty + i * 8) * C + gx + tx];
    __syncthreads();
#pragma unroll
    for (int i = 0; i < 4; ++i)
        out[(size_t)(gx + ty + i * 8) * R + gy + tx] = f2bf(tile[tx][ty + i * 8]);
}

// ---------------------------------------------------------------------------
// Transpose V: v [32][2048][64] bf16 -> vt [32][64][2048] bf16
// ---------------------------------------------------------------------------
__global__ __launch_bounds__(256) void transpose_v(const short* __restrict__ v,
                                                   short* __restrict__ vt) {
    const int bh = blockIdx.y;
    const int n0 = blockIdx.x * 64;
    __shared__ short tile[64 * 72];
    const int r = threadIdx.x >> 3;          // 0..31
    const int c8 = (threadIdx.x & 7) * 8;    // 0..56
#pragma unroll
    for (int p = 0; p < 2; ++p)
        *(bf16x8*)&tile[(p * 32 + r) * 72 + c8] =
            *(const bf16x8*)&v[((size_t)bh * NSEQ + n0 + p * 32 + r) * DHEAD + c8];
    __syncthreads();
#pragma unroll
    for (int p = 0; p < 2; ++p) {
        const int d = p * 32 + r;
        bf16x8 o;
#pragma unroll
        for (int j = 0; j < 8; ++j) o[j] = tile[(c8 + j) * 72 + d];
        *(bf16x8*)&vt[((size_t)bh * DHEAD + d) * NSEQ + n0 + c8] = o;
    }
}

// ---------------------------------------------------------------------------
// GEMM: C[M x N] = A[M x K] * Bt[N x K]^T, bf16 in, fp32 acc.
// m97 structure: global_load_lds width-16 staging, unpadded 128x32 LDS tiles.
// MODE 0: scatter to q/k/v [3][b*h][n][d] bf16, scale q by d^-0.5.
// MODE 1: fp32 row-major output.
// ---------------------------------------------------------------------------
template <int MODE>
__global__ __launch_bounds__(256) void gemm_bt(const short* __restrict__ A,
                                               const short* __restrict__ Bt,
                                               void* __restrict__ Cout,
                                               int K, int N) {
    __shared__ alignas(16) short lds_a[128 * 32];   // unpadded: global_load_lds contract
    __shared__ alignas(16) short lds_b[128 * 32];
    const int tid = threadIdx.x;
    const int lane = tid & 63, wid = tid >> 6;
    const int quad = lane >> 4, l16 = lane & 15;
    const int wm = wid >> 1, wn = wid & 1;
    const int mb = blockIdx.y * 128, nb = blockIdx.x * 128;

    f32x4 acc[4][4];
#pragma unroll
    for (int i = 0; i < 4; ++i)
#pragma unroll
        for (int j = 0; j < 4; ++j) acc[i][j] = (f32x4){0.f, 0.f, 0.f, 0.f};

    // staging map: wave w covers rows w*32..w*32+31 via two 16-row calls;
    // lane l -> row base + l/4, col (l&3)*8 shorts; lds off = base + lane*16B
    const int lr = lane >> 2;
    const int lc = (lane & 3) * 8;
    const int r0 = wid * 32 + lr, r1 = wid * 32 + 16 + lr;

    for (int kb = 0; kb < K; kb += 32) {
        __syncthreads();   // all waves done reading previous tile
        async_copy16(&A[(size_t)(mb + r0) * K + kb + lc], &lds_a[r0 * 32 + lc]);
        async_copy16(&A[(size_t)(mb + r1) * K + kb + lc], &lds_a[r1 * 32 + lc]);
        async_copy16(&Bt[(size_t)(nb + r0) * K + kb + lc], &lds_b[r0 * 32 + lc]);
        async_copy16(&Bt[(size_t)(nb + r1) * K + kb + lc], &lds_b[r1 * 32 + lc]);
        __syncthreads();   // compiler drains vmcnt before barrier
        bf16x8 af[4], bfr[4];
#pragma unroll
        for (int mt = 0; mt < 4; ++mt)
            af[mt] = *(const bf16x8*)&lds_a[(wm * 64 + mt * 16 + l16) * 32 + quad * 8];
#pragma unroll
        for (int nt = 0; nt < 4; ++nt)
            bfr[nt] = *(const bf16x8*)&lds_b[(wn * 64 + nt * 16 + l16) * 32 + quad * 8];
#pragma unroll
        for (int mt = 0; mt < 4; ++mt)
#pragma unroll
            for (int nt = 0; nt < 4; ++nt)
                acc[mt][nt] = __builtin_amdgcn_mfma_f32_16x16x32_bf16(af[mt], bfr[nt],
                                                                      acc[mt][nt], 0, 0, 0);
    }

#pragma unroll
    for (int mt = 0; mt < 4; ++mt) {
#pragma unroll
        for (int nt = 0; nt < 4; ++nt) {
#pragma unroll
            for (int r = 0; r < 4; ++r) {
                const int grow = mb + wm * 64 + mt * 16 + quad * 4 + r;
                const int gcol = nb + wn * 64 + nt * 16 + l16;
                const float val = acc[mt][nt][r];
                if (MODE == 0) {
                    const int s3 = gcol >> 10, rem = gcol & 1023;
                    const int hh = rem >> 6, dd = rem & 63;
                    const int bb = grow >> 11, npos = grow & 2047;
                    const float vq = (s3 == 0) ? val * 0.125f : val;   // q * d^-0.5
                    ((short*)Cout)[(size_t)((s3 * 32 + bb * 16 + hh) * 2048 + npos) * 64 + dd] =
                        f2bf(vq);
                } else {
                    ((float*)Cout)[(size_t)grow * N + gcol] = val;
                }
            }
        }
    }
}

// ---------------------------------------------------------------------------
// Causal flash attention, S^T formulation, zero block barriers.
// q,k: [32][2048][64] bf16 (q pre-scaled). vt: [32][64][2048] bf16.
// S^T = K Q^T  => C-layout lane: col(l16)=QUERY, row(quad*4+r)=KEY.
// Softmax row-reduce = 15 in-register ops + 2 cross-lane (xor16/xor32).
// O^T = V^T P  => lane: col(l16)=QUERY, row(quad*4+r)=d  -> packed b64 stores.
// Each wave: mirrored chunk pair (qc, 63-qc) = exactly 33 key-tiles (uniform).
// ---------------------------------------------------------------------------
__global__ __launch_bounds__(256, 1) void attn_kernel(const short* __restrict__ qg,
                                                      const short* __restrict__ kg,
                                                      const short* __restrict__ vtg,
                                                      short* __restrict__ og) {
    const int tid = threadIdx.x;
    const int wid = tid >> 6, lane = tid & 63;
    const int quad = lane >> 4, l16 = lane & 15;
    const int gw = blockIdx.x * 4 + wid;        // 0..1023
    const int bh = gw >> 5;                     // 0..31
    const int pc = gw & 31;                     // pair index
    const size_t base = (size_t)bh * (NSEQ * DHEAD);
    const int bb = bh >> 4, hh = bh & 15;

    __shared__ alignas(16) short pbuf[4][32 * 72];   // wave-private, stride 72 (16B-aligned rows)
    short* const pb = pbuf[wid];

    for (int half = 0; half < 2; ++half) {
        const int qc = half ? (63 - pc) : pc;   // 32-query chunk
        const int qbase = qc * 32;
        const int ntiles = (qc >> 1) + 1;       // 64-key tiles

        // Q fragments (B-operand): lane n=l16 -> query qbase+qn*16+l16, k=quad*8+j
        bf16x8 qf[2][2];
#pragma unroll
        for (int qn = 0; qn < 2; ++qn)
#pragma unroll
            for (int kh = 0; kh < 2; ++kh)
                qf[qn][kh] = *(const bf16x8*)&qg[base + (size_t)(qbase + qn * 16 + l16) * DHEAD +
                                                kh * 32 + quad * 8];

        float mi[2], li[2];
        f32x4 accO[2][4];
#pragma unroll
        for (int qn = 0; qn < 2; ++qn) {
            mi[qn] = -3.0e38f; li[qn] = 0.f;
#pragma unroll
            for (int nc = 0; nc < 4; ++nc) accO[qn][nc] = (f32x4){0.f, 0.f, 0.f, 0.f};
        }

        // K fragments (A-operand) for tile 0; prefetched each iteration
        bf16x8 kf[4][2];
#pragma unroll
        for (int m = 0; m < 4; ++m) {
            const short* kr = &kg[base + (size_t)(m * 16 + l16) * DHEAD];
            kf[m][0] = *(const bf16x8*)&kr[quad * 8];
            kf[m][1] = *(const bf16x8*)&kr[32 + quad * 8];
        }

        for (int t = 0; t < ntiles; ++t) {
            const int kb = t * 64;

            // ---- S^T = K Q^T : 16 MFMAs ----
            f32x4 sf[2][4];
#pragma unroll
            for (int m = 0; m < 4; ++m)
#pragma unroll
                for (int qn = 0; qn < 2; ++qn) {
                    f32x4 z = (f32x4){0.f, 0.f, 0.f, 0.f};
                    z = __builtin_amdgcn_mfma_f32_16x16x32_bf16(kf[m][0], qf[qn][0], z, 0, 0, 0);
                    sf[qn][m] = __builtin_amdgcn_mfma_f32_16x16x32_bf16(kf[m][1], qf[qn][1], z,
                                                                        0, 0, 0);
                }

            // ---- prefetch next K tile (hidden behind softmax + PV) ----
            if (t + 1 < ntiles) {
#pragma unroll
                for (int m = 0; m < 4; ++m) {
                    const short* kr = &kg[base + (size_t)(kb + 64 + m * 16 + l16) * DHEAD];
                    kf[m][0] = *(const bf16x8*)&kr[quad * 8];
                    kf[m][1] = *(const bf16x8*)&kr[32 + quad * 8];
                }
            }
            // ---- V^T fragments for this tile (issued before softmax) ----
            bf16x8 vf[4][2];
#pragma unroll
            for (int nc = 0; nc < 4; ++nc) {
                const short* vr = &vtg[base + (size_t)(nc * 16 + l16) * NSEQ + kb];
                vf[nc][0] = *(const bf16x8*)&vr[quad * 8];
                vf[nc][1] = *(const bf16x8*)&vr[32 + quad * 8];
            }

            // ---- causal mask (diagonal tile only; wave-uniform branch) ----
            if (kb + 64 > qbase) {
#pragma unroll
                for (int qn = 0; qn < 2; ++qn) {
                    const int myq = qbase + qn * 16 + l16;
#pragma unroll
                    for (int m = 0; m < 4; ++m)
#pragma unroll
                        for (int r = 0; r < 4; ++r)
                            if (kb + m * 16 + quad * 4 + r > myq) sf[qn][m][r] = -3.0e38f;
                }
            }

            // ---- online softmax: per-lane column = one query ----
#pragma unroll
            for (int qn = 0; qn < 2; ++qn) {
                f32x4 t4;
#pragma unroll
                for (int e = 0; e < 4; ++e)
                    t4[e] = fmaxf(fmaxf(sf[qn][0][e], sf[qn][1][e]),
                                  fmaxf(sf[qn][2][e], sf[qn][3][e]));
                float rm = fmaxf(fmaxf(t4[0], t4[1]), fmaxf(t4[2], t4[3]));
                rm = fmaxf(rm, __shfl_xor(rm, 16, 64));
                rm = fmaxf(rm, __shfl_xor(rm, 32, 64));
                const float nm = fmaxf(mi[qn], rm);
                const float al = __expf(mi[qn] - nm);
                mi[qn] = nm;
                float rs = 0.f;
#pragma unroll
                for (int m = 0; m < 4; ++m)
#pragma unroll
                    for (int r = 0; r < 4; ++r) {
                        const float p = __expf(sf[qn][m][r] - nm);
                        sf[qn][m][r] = p;
                        rs += p;
                    }
                rs += __shfl_xor(rs, 16, 64);
                rs += __shfl_xor(rs, 32, 64);
                li[qn] = li[qn] * al + rs;
#pragma unroll
                for (int nc = 0; nc < 4; ++nc)
#pragma unroll
                    for (int r = 0; r < 4; ++r) accO[qn][nc][r] *= al;

                // pack P row (query l16): keys m*16+quad*4..+3 -> b64 LDS writes
#pragma unroll
                for (int m = 0; m < 4; ++m) {
                    bf16x4 pw;
#pragma unroll
                    for (int r = 0; r < 4; ++r) pw[r] = f2bf(sf[qn][m][r]);
                    *(bf16x4*)&pb[(qn * 16 + l16) * 72 + m * 16 + quad * 4] = pw;
                }
            }

            // ---- B-fragments of P (same-wave LDS RAW, lgkmcnt-ordered) ----
            bf16x8 pf[2][2];
#pragma unroll
            for (int qn = 0; qn < 2; ++qn)
#pragma unroll
                for (int kh = 0; kh < 2; ++kh)
                    pf[qn][kh] = *(const bf16x8*)&pb[(qn * 16 + l16) * 72 + kh * 32 + quad * 8];

            // ---- O^T += V^T P : 16 MFMAs ----
#pragma unroll
            for (int nc = 0; nc < 4; ++nc)
#pragma unroll
                for (int qn = 0; qn < 2; ++qn) {
                    accO[qn][nc] = __builtin_amdgcn_mfma_f32_16x16x32_bf16(vf[nc][0], pf[qn][0],
                                                                          accO[qn][nc], 0, 0, 0);
                    accO[qn][nc] = __builtin_amdgcn_mfma_f32_16x16x32_bf16(vf[nc][1], pf[qn][1],
                                                                          accO[qn][nc], 0, 0, 0);
                }
        }

        // ---- epilogue: O^T lane = query l16; d = nc*16+quad*4+r -> b64 stores ----
#pragma unroll
        for (int qn = 0; qn < 2; ++qn) {
            const float inv = 1.0f / li[qn];
            const int npos = qbase + qn * 16 + l16;
#pragma unroll
            for (int nc = 0; nc < 4; ++nc) {
                bf16x4 ow;
#pragma unroll
                for (int r = 0; r < 4; ++r) ow[r] = f2bf(accO[qn][nc][r] * inv);
                *(bf16x4*)&og[(size_t)(bb * 2048 + npos) * 1024 + hh * 64 + nc * 16 + quad * 4] = ow;
            }
        }
    }
}

// ---------------------------------------------------------------------------
// Launch
// ---------------------------------------------------------------------------
extern "C" void kernel_launch(void* const* d_in, const int* in_sizes, int n_in,
                              void* d_out, int out_size, void* d_ws, size_t ws_size,
                              hipStream_t stream) {
    const float* x     = (const float*)d_in[0];
    const float* gamma = (const float*)d_in[1];
    const float* w_qkv = (const float*)d_in[2];
    const float* w_out = (const float*)d_in[3];
    float* out = (float*)d_out;
    char* ws = (char*)d_ws;

    short* xn     = (short*)(ws);                    //  8 MB (dead after gemm<0>)
    short* vt     = (short*)(ws);                    //  8 MB (reuses xn)
    short* wqkvT  = (short*)(ws + 8388608);          //  6 MB
    short* woutT  = (short*)(ws + 14680064);         //  2 MB
    short* q      = (short*)(ws + 16777216);         // 24 MB: [3][32][2048][64]
    short* k      = q + 32 * 2048 * 64;
    short* v      = k + 32 * 2048 * 64;
    short* attn   = (short*)(ws + 41943040);         //  8 MB

    transpose_cast<<<dim3(NQKV / 32, DIM / 32), 256, 0, stream>>>(w_qkv, wqkvT, DIM, NQKV);
    transpose_cast<<<dim3(DIM / 32, DIM / 32), 256, 0, stream>>>(w_out, woutT, DIM, DIM);
    rmsnorm_kernel<<<ROWS, 256, 0, stream>>>(x, gamma, xn);
    gemm_bt<0><<<dim3(NQKV / 128, ROWS / 128), 256, 0, stream>>>(xn, wqkvT, q, DIM, NQKV);
    transpose_v<<<dim3(NSEQ / 64, 32), 256, 0, stream>>>(v, vt);
    attn_kernel<<<256, 256, 0, stream>>>(q, k, vt, attn);
    gemm_bt<1><<<dim3(DIM / 128, ROWS / 128), 256, 0, stream>>>(attn, woutT, out, DIM, DIM);
}